// Round 1
// baseline (679.797 us; speedup 1.0000x reference)
//
#include <hip/hip_runtime.h>

#define NSEG 256
#define D 128
#define COL4 (D / 4)   // 32 float4 per row
#define SPLIT 16       // blocks per segment in the partial-sum kernel

// ws layout:
//   [0 .. 1028)                : int starts[NSEG+1]
//   [4096 .. 4096 + 2 MiB)     : float4 psums[SPLIT][NSEG][COL4]

__global__ void init_starts_kernel(int* starts, int n) {
    int i = blockIdx.x * blockDim.x + threadIdx.x;
    if (i <= NSEG) starts[i] = n;
}

__global__ void find_starts_kernel(const int* __restrict__ seg, int n, int* __restrict__ starts) {
    int i = blockIdx.x * blockDim.x + threadIdx.x;
    if (i < n) {
        int s = seg[i];
        if (i == 0 || seg[i - 1] != s) starts[s] = i;
    }
}

// Grid: NSEG*SPLIT blocks x 256 threads. Block (s,k) reduces a contiguous
// chunk of segment s into psums[k][s][*]. No atomics; deterministic.
__global__ __launch_bounds__(256) void seg_partial_kernel(const float4* __restrict__ inp,
                                                          const int* __restrict__ starts,
                                                          float4* __restrict__ psums, int n) {
    const int s = blockIdx.x >> 4;            // / SPLIT
    const int k = blockIdx.x & (SPLIT - 1);

    __shared__ int sh_bounds[2];
    if (threadIdx.x == 0) {
        int st = starts[s];
        int en = n;
        // next valid start (all segments present by construction -> exits on first probe)
        for (int t = s + 1; t <= NSEG; ++t) {
            int v = starts[t];
            if (v < n) { en = v; break; }
        }
        sh_bounds[0] = st;
        sh_bounds[1] = en;
    }
    __syncthreads();
    const int start = sh_bounds[0];
    const int end   = sh_bounds[1];

    int len = end - start;
    if (len < 0) len = 0;                     // absent-segment guard (never by construction)
    const int chunk = (len + SPLIT - 1) / SPLIT;
    int r0 = start + k * chunk;
    int r1 = r0 + chunk;
    if (r1 > end) r1 = end;

    const int col  = threadIdx.x & (COL4 - 1);   // float4 column 0..31
    const int slot = threadIdx.x >> 5;           // row slot 0..7

    float4 acc = make_float4(0.f, 0.f, 0.f, 0.f);
    // wave = 2 rows x 512 B contiguous per load instruction; coalesced
    #pragma unroll 4
    for (int r = r0 + slot; r < r1; r += 8) {
        float4 v = inp[(size_t)r * COL4 + col];
        acc.x += v.x; acc.y += v.y; acc.z += v.z; acc.w += v.w;
    }

    // 8-slot tree reduction in LDS (4 KiB)
    __shared__ float4 red[8][COL4];
    red[slot][col] = acc;
    __syncthreads();
    #pragma unroll
    for (int stride = 4; stride >= 1; stride >>= 1) {
        if (slot < stride) {
            float4 a = red[slot][col];
            float4 b = red[slot + stride][col];
            a.x += b.x; a.y += b.y; a.z += b.z; a.w += b.w;
            red[slot][col] = a;
        }
        __syncthreads();
    }

    if (slot == 0) {
        psums[((size_t)k * NSEG + s) * COL4 + col] = red[0][col];
    }
}

// Grid: NSEG/2 blocks x 64 threads. Each wave-half handles one segment:
// sum the SPLIT partials (2 MiB total read), divide by count, write out.
__global__ __launch_bounds__(64) void finalize_kernel(const float4* __restrict__ psums,
                                                      const int* __restrict__ starts,
                                                      float4* __restrict__ out, int n) {
    const int s   = blockIdx.x * 2 + (threadIdx.x >> 5);
    const int col = threadIdx.x & 31;

    int start = starts[s];
    int end = n;
    for (int t = s + 1; t <= NSEG; ++t) {
        int v = starts[t];
        if (v < n) { end = v; break; }
    }
    int cnt = end - start;                    // may be <=0 for absent segment -> output 0
    float inv = 1.0f / (float)(cnt > 1 ? cnt : 1);

    float4 a = make_float4(0.f, 0.f, 0.f, 0.f);
    #pragma unroll
    for (int k = 0; k < SPLIT; ++k) {
        float4 v = psums[((size_t)k * NSEG + s) * COL4 + col];
        a.x += v.x; a.y += v.y; a.z += v.z; a.w += v.w;
    }
    out[(size_t)s * COL4 + col] = make_float4(a.x * inv, a.y * inv, a.z * inv, a.w * inv);
}

extern "C" void kernel_launch(void* const* d_in, const int* in_sizes, int n_in,
                              void* d_out, int out_size, void* d_ws, size_t ws_size,
                              hipStream_t stream) {
    const float* inp = (const float*)d_in[0];
    const int* seg   = (const int*)d_in[1];
    float* out       = (float*)d_out;
    const int n = in_sizes[1];                // 1048576 rows

    int* starts    = (int*)d_ws;              // NSEG+1 ints
    float4* psums  = (float4*)((char*)d_ws + 4096);  // SPLIT*NSEG*COL4 float4 = 2 MiB

    init_starts_kernel<<<2, 256, 0, stream>>>(starts, n);
    find_starts_kernel<<<(n + 255) / 256, 256, 0, stream>>>(seg, n, starts);
    seg_partial_kernel<<<NSEG * SPLIT, 256, 0, stream>>>((const float4*)inp, starts, psums, n);
    finalize_kernel<<<NSEG / 2, 64, 0, stream>>>(psums, starts, (float4*)out, n);
}

// Round 2
// 658.357 us; speedup vs baseline: 1.0326x; 1.0326x over previous
//
#include <hip/hip_runtime.h>

#define NSEG 256
#define D 128
#define COL4 (D / 4)          // 32 float4 per row
#define ROWS_PER_CHUNK 512
#define MAIN_BLOCKS 2048      // 8 blocks/CU co-residency cap (G11)

typedef float f32x4 __attribute__((ext_vector_type(4)));

// ws layout:
//   [0 .. 128 KiB)            : float sums[NSEG*D]
//   [128 KiB .. 128 KiB+1 KiB): int   cnt[NSEG]

__global__ __launch_bounds__(256) void zero_ws(float* __restrict__ sums, int* __restrict__ cnt) {
    int i = blockIdx.x * 256 + threadIdx.x;
    if (i < NSEG * D) sums[i] = 0.f;
    if (i < NSEG) cnt[i] = 0;
}

// Grid-stride over 512-row chunks. Each block stages the chunk's seg ids in LDS,
// streams the rows with nontemporal float4 loads (zero reuse -> don't pollute the
// fill-dirtied L2/L3), and merges partials into sums[] via f32 atomics.
// Fast path (no segment boundary in chunk, ~75% of chunks): LDS tree reduction,
// 128 atomics/block. Slow path: per-thread run detection + flush.
__global__ __launch_bounds__(256) void seg_sum_kernel(const f32x4* __restrict__ inp,
                                                      const int* __restrict__ seg,
                                                      float* __restrict__ sums,
                                                      int* __restrict__ cnt, int n) {
    __shared__ int  sh_seg[ROWS_PER_CHUNK];
    __shared__ f32x4 red[8][COL4];

    const int tid  = threadIdx.x;
    const int col  = tid & (COL4 - 1);   // float4 column 0..31
    const int slot = tid >> 5;           // row slot 0..7
    const int nchunks = (n + ROWS_PER_CHUNK - 1) / ROWS_PER_CHUNK;

    for (int c = blockIdx.x; c < nchunks; c += gridDim.x) {
        const int base = c * ROWS_PER_CHUNK;
        const int rows = min(ROWS_PER_CHUNK, n - base);

        // stage seg ids (coalesced int2)
        if (rows == ROWS_PER_CHUNK) {
            ((int2*)sh_seg)[tid] = ((const int2*)(seg + base))[tid];
        } else {
            for (int j = tid; j < rows; j += 256) sh_seg[j] = seg[base + j];
        }
        __syncthreads();

        const bool uniform = (sh_seg[0] == sh_seg[rows - 1]);

        if (uniform) {
            const int sid = sh_seg[0];
            f32x4 acc = {0.f, 0.f, 0.f, 0.f};
            #pragma unroll 4
            for (int r = slot; r < rows; r += 8) {
                f32x4 v = __builtin_nontemporal_load(&inp[(size_t)(base + r) * COL4 + col]);
                acc += v;
            }
            red[slot][col] = acc;
            __syncthreads();
            #pragma unroll
            for (int st = 4; st >= 1; st >>= 1) {
                if (slot < st) red[slot][col] += red[slot + st][col];
                __syncthreads();
            }
            if (slot == 0) {
                f32x4 a = red[0][col];
                atomicAdd(&sums[sid * D + col * 4 + 0], a[0]);
                atomicAdd(&sums[sid * D + col * 4 + 1], a[1]);
                atomicAdd(&sums[sid * D + col * 4 + 2], a[2]);
                atomicAdd(&sums[sid * D + col * 4 + 3], a[3]);
                if (col == 0) atomicAdd(&cnt[sid], rows);
            }
            __syncthreads();   // red[] / sh_seg reuse next chunk
        } else {
            f32x4 acc = {0.f, 0.f, 0.f, 0.f};
            int cur = -1, runcnt = 0;
            for (int r = slot; r < rows; r += 8) {
                int sid = sh_seg[r];   // broadcast across the 32 col-lanes
                if (sid != cur) {
                    if (runcnt) {
                        atomicAdd(&sums[cur * D + col * 4 + 0], acc[0]);
                        atomicAdd(&sums[cur * D + col * 4 + 1], acc[1]);
                        atomicAdd(&sums[cur * D + col * 4 + 2], acc[2]);
                        atomicAdd(&sums[cur * D + col * 4 + 3], acc[3]);
                        if (col == 0) atomicAdd(&cnt[cur], runcnt);
                    }
                    cur = sid;
                    acc = (f32x4){0.f, 0.f, 0.f, 0.f};
                    runcnt = 0;
                }
                f32x4 v = __builtin_nontemporal_load(&inp[(size_t)(base + r) * COL4 + col]);
                acc += v;
                runcnt++;
            }
            if (runcnt) {
                atomicAdd(&sums[cur * D + col * 4 + 0], acc[0]);
                atomicAdd(&sums[cur * D + col * 4 + 1], acc[1]);
                atomicAdd(&sums[cur * D + col * 4 + 2], acc[2]);
                atomicAdd(&sums[cur * D + col * 4 + 3], acc[3]);
                if (col == 0) atomicAdd(&cnt[cur], runcnt);
            }
            __syncthreads();   // sh_seg reuse next chunk
        }
    }
}

__global__ __launch_bounds__(256) void finalize_kernel(const float* __restrict__ sums,
                                                       const int* __restrict__ cnt,
                                                       float* __restrict__ out) {
    int i = blockIdx.x * 256 + threadIdx.x;   // 0 .. NSEG*D-1
    int s = i >> 7;                           // / D
    int c = cnt[s];
    float inv = 1.0f / (float)(c > 1 ? c : 1);
    out[i] = sums[i] * inv;
}

extern "C" void kernel_launch(void* const* d_in, const int* in_sizes, int n_in,
                              void* d_out, int out_size, void* d_ws, size_t ws_size,
                              hipStream_t stream) {
    const float* inp = (const float*)d_in[0];
    const int* seg   = (const int*)d_in[1];
    float* out       = (float*)d_out;
    const int n = in_sizes[1];                // 1048576 rows

    float* sums = (float*)d_ws;                        // NSEG*D floats = 128 KiB
    int* cnt    = (int*)((char*)d_ws + NSEG * D * 4);  // NSEG ints

    zero_ws<<<(NSEG * D + 255) / 256, 256, 0, stream>>>(sums, cnt);

    int nchunks = (n + ROWS_PER_CHUNK - 1) / ROWS_PER_CHUNK;
    int grid = nchunks < MAIN_BLOCKS ? nchunks : MAIN_BLOCKS;
    seg_sum_kernel<<<grid, 256, 0, stream>>>((const f32x4*)inp, seg, sums, cnt, n);

    finalize_kernel<<<(NSEG * D + 255) / 256, 256, 0, stream>>>(sums, cnt, out);
}